// Round 7
// baseline (270.199 us; speedup 1.0000x reference)
//
#include <hip/hip_runtime.h>

typedef _Float16 f16;
typedef _Float16 h8 __attribute__((ext_vector_type(8)));
typedef float f4 __attribute__((ext_vector_type(4)));

typedef const __attribute__((address_space(1))) char gchar;
typedef __attribute__((address_space(3))) char lchar;

#define B_ 4
#define S_ 2048
#define D_ 1024
#define H_ 1024

template <int N>
__device__ __forceinline__ void vmwait() {
  if constexpr (N == 0) asm volatile("s_waitcnt vmcnt(0)" ::: "memory");
  else if constexpr (N == 8) asm volatile("s_waitcnt vmcnt(8)" ::: "memory");
}

// ---------------- fused fp32 -> fp16 cast of all six inputs ----------------
#define NGX (8388608L / 8)
#define NGW (1048576L / 8)

__global__ __launch_bounds__(256) void cast_all(
    const float* __restrict__ x1, const float* __restrict__ x2, const float* __restrict__ x3,
    const float* __restrict__ wq, const float* __restrict__ wk, const float* __restrict__ wv,
    f16* __restrict__ o1, f16* __restrict__ o2, f16* __restrict__ o3,
    f16* __restrict__ o4, f16* __restrict__ o5, f16* __restrict__ o6) {
  const long NG = 3 * NGX + 3 * NGW;
  long g = blockIdx.x * 256L + threadIdx.x;
  const long stride = (long)gridDim.x * 256L;
  for (; g < NG; g += stride) {
    const float* in;
    f16* out;
    long off;
    if (g < 3 * NGX) {
      const long w = g >> 20;
      off = (g - w * NGX) * 8;
      in = w == 0 ? x1 : (w == 1 ? x2 : x3);
      out = w == 0 ? o1 : (w == 1 ? o2 : o3);
    } else {
      const long gg = g - 3 * NGX;
      const long h = gg >> 17;
      off = (gg - h * NGW) * 8;
      in = h == 0 ? wq : (h == 1 ? wk : wv);
      out = h == 0 ? o4 : (h == 1 ? o5 : o6);
    }
    float4 u = *(const float4*)(in + off);
    float4 v = *(const float4*)(in + off + 4);
    h8 o;
    o[0] = (f16)u.x; o[1] = (f16)u.y; o[2] = (f16)u.z; o[3] = (f16)u.w;
    o[4] = (f16)v.x; o[5] = (f16)v.y; o[6] = (f16)v.z; o[7] = (f16)v.w;
    *(h8*)(out + off) = o;
  }
}

// ---------- 256x256 GEMM C = A * B^T : BK=32, 4-slot ring (128 KiB), 2 phases/K-tile ----------
// A [M,K], B [N,K] f16 row-major. 512 thr = 8 waves (2M x 4N), per-wave C = 128x64.
// Slot s = t&3 holds K-tile t (A: 8192 f16, B: 8192 f16). Iter t stages tile t+3 into slot
// (t+3)&3 = slot of t-1 (reads done before iter t-1's last barrier). vmcnt(8) once per K-tile
// retires tile t+1 (t+2's 4 + t+3's 4 calls remain in flight). Never drains to 0 in-loop.
// Swizzle (both-sides, involution): content (row r, 16B-granule g) stored in row-pair rp=r>>1
// at slot s8 = (4*(r&1)+g) ^ (rp&7) -> 16-lane fragment reads are conflict-free; DMA dest
// stays linear (wave-uniform base + lane*16B); global source pre-swizzled.
// MODE 0: f32 C[m*N+n] (+bz*sC).
// MODE 3: proj batched: bz<2 -> f16 C[m*N+n] (+bz*sC); bz==2 -> V^T C[((m>>11)*N+col)*2048+(m&2047)].
template <int MODE>
__global__ __launch_bounds__(512, 2) void gemm256p(const f16* __restrict__ A,
                                                   const f16* __restrict__ Bm,
                                                   void* __restrict__ C,
                                                   int N, int K,
                                                   long sA, long sB, long sC,
                                                   int gx, int gy) {
  extern __shared__ __align__(16) f16 smem[];  // 4 slots x 16384 f16 = 131072 B

  // bijective XCD swizzle (grid % 8 == 0); by fastest
  const int cpx = gridDim.x >> 3;
  const int wgid = (blockIdx.x & 7) * cpx + (blockIdx.x >> 3);
  const int by = wgid % gy;
  const int bx = (wgid / gy) % gx;
  const int bz = wgid / (gy * gx);
  A += (long)bz * sA;
  Bm += (long)bz * sB;
  const int m0 = bx * 256, n0 = by * 256;

  const int tid = threadIdx.x;
  const int lane = tid & 63;
  const int w = tid >> 6;           // 0..7
  const int wm = w >> 2, wn = w & 3;
  const int fr = lane & 15;
  const int gq = lane >> 4;         // k-granule 0..3 (8 f16)

  // staging source mapping (thread tid covers stored pos tid*8 f16 of a 128-row call):
  const int srp = tid >> 3;         // row-pair within call (0..63)
  const int ss8 = tid & 7;          // stored granule slot
  const int su = ss8 ^ (srp & 7);   // content index: b = su>>2, g = su&3
  const int sdr = (srp << 1) | (su >> 2);   // source row within call's 128 rows
  const int sdc = (su & 3) * 8;             // source col f16 within K-tile

  // stage one matrix half (128 rows) of K-tile t into slot sl; c = half (0/1), mat: 0=A,1=B
  auto STAGE = [&](int sl, int t, int mat, int c) {
    const f16* src = (mat == 0 ? A : Bm);
    const int r0 = (mat == 0 ? m0 : n0) + c * 128;
    __builtin_amdgcn_global_load_lds(
        (gchar*)(src + (long)(r0 + sdr) * K + t * 32 + sdc),
        (lchar*)(smem + sl * 16384 + mat * 8192 + c * 4096 + w * 512), 16, 0, 0);
  };

  auto RDA = [&](int sl, int r) -> h8 {
    const int rp = r >> 1;
    const int s8 = ((((r & 1) << 2) | gq) ^ (rp & 7));
    return *(const h8*)(smem + sl * 16384 + rp * 64 + s8 * 8);
  };
  auto RDB = [&](int sl, int r) -> h8 {
    const int rp = r >> 1;
    const int s8 = ((((r & 1) << 2) | gq) ^ (rp & 7));
    return *(const h8*)(smem + sl * 16384 + 8192 + rp * 64 + s8 * 8);
  };

  f4 acc[8][4] = {};
  const int NT = K >> 5;

  // prologue: tiles 0,1,2 -> slots 0,1,2 (4 calls each)
  const int t1 = NT > 1 ? 1 : 0, t2 = NT > 2 ? 2 : 0;
  STAGE(0, 0, 0, 0); STAGE(0, 0, 0, 1); STAGE(0, 0, 1, 0); STAGE(0, 0, 1, 1);
  STAGE(1, t1, 0, 0); STAGE(1, t1, 0, 1); STAGE(1, t1, 1, 0); STAGE(1, t1, 1, 1);
  STAGE(2, t2, 0, 0); STAGE(2, t2, 0, 1); STAGE(2, t2, 1, 0); STAGE(2, t2, 1, 1);
  vmwait<8>();                      // tile 0 landed; 1,2 in flight
  __builtin_amdgcn_s_barrier();

  for (int t = 0; t < NT; ++t) {
    const int sl = t & 3;
    const int ts = (t + 3 < NT) ? t + 3 : NT - 1;  // tail dups land in freed slots, never read
    const int sd = (t + 3) & 3;

    // ---- phase 0: mi 0..3 + all B frags; stage A-half calls of tile t+3 ----
    h8 af[4], bf[4];
#pragma unroll
    for (int mi = 0; mi < 4; ++mi) af[mi] = RDA(sl, wm * 128 + mi * 16 + fr);
#pragma unroll
    for (int ni = 0; ni < 4; ++ni) bf[ni] = RDB(sl, wn * 64 + ni * 16 + fr);
    STAGE(sd, ts, 0, 0); STAGE(sd, ts, 0, 1);
    __builtin_amdgcn_s_barrier();
    asm volatile("s_waitcnt lgkmcnt(0)" ::: "memory");
    __builtin_amdgcn_sched_barrier(0);
    __builtin_amdgcn_s_setprio(1);
#pragma unroll
    for (int mi = 0; mi < 4; ++mi)
#pragma unroll
      for (int ni = 0; ni < 4; ++ni)
        acc[mi][ni] = __builtin_amdgcn_mfma_f32_16x16x32_f16(af[mi], bf[ni], acc[mi][ni], 0, 0, 0);
    __builtin_amdgcn_s_setprio(0);
    __builtin_amdgcn_s_barrier();

    // ---- phase 1: mi 4..7 (bf reused from regs); stage B-half calls; counted vmcnt ----
#pragma unroll
    for (int mi = 0; mi < 4; ++mi) af[mi] = RDA(sl, wm * 128 + (mi + 4) * 16 + fr);
    STAGE(sd, ts, 1, 0); STAGE(sd, ts, 1, 1);
    vmwait<8>();                    // tile t+1 fully landed; t+2 (4) + t+3 (4) in flight
    __builtin_amdgcn_s_barrier();
    asm volatile("s_waitcnt lgkmcnt(0)" ::: "memory");
    __builtin_amdgcn_sched_barrier(0);
    __builtin_amdgcn_s_setprio(1);
#pragma unroll
    for (int mi = 0; mi < 4; ++mi)
#pragma unroll
      for (int ni = 0; ni < 4; ++ni)
        acc[mi + 4][ni] = __builtin_amdgcn_mfma_f32_16x16x32_f16(af[mi], bf[ni], acc[mi + 4][ni], 0, 0, 0);
    __builtin_amdgcn_s_setprio(0);
    __builtin_amdgcn_s_barrier();
  }
  vmwait<0>();  // drain DMA before LDS dealloc

  // epilogue: C/D layout (measured): col = lane&15, row = (lane>>4)*4 + reg
  const int fq = gq * 4;
#pragma unroll
  for (int mi = 0; mi < 8; ++mi) {
#pragma unroll
    for (int ni = 0; ni < 4; ++ni) {
#pragma unroll
      for (int i = 0; i < 4; ++i) {
        const int row = m0 + wm * 128 + mi * 16 + fq + i;
        const int col = n0 + wn * 64 + ni * 16 + fr;
        const float val = acc[mi][ni][i];
        if constexpr (MODE == 0) {
          float* Cp = (float*)C + (long)bz * sC;
          Cp[(long)row * N + col] = val;
        } else {
          if (bz < 2) {
            f16* Cp = (f16*)C + (long)bz * sC;
            Cp[(long)row * N + col] = (f16)val;
          } else {
            f16* Cp = (f16*)C + 2 * sC;
            Cp[((long)(row >> 11) * N + col) * 2048 + (row & 2047)] = (f16)val;
          }
        }
      }
    }
  }
}

// ---------------- fused scale + mask + softmax, scores f32 -> P f16 ----------------
__global__ __launch_bounds__(256) void softmax_rows(const float* __restrict__ Sc,
                                                    const float* __restrict__ mask,
                                                    f16* __restrict__ P, float scale) {
  const long row = blockIdx.x;
  const float* s = Sc + row * (long)S_;
  const float* mk = mask + row * (long)S_;
  const int t = threadIdx.x;

  float4 a0 = *(const float4*)(s + t * 8);
  float4 a1 = *(const float4*)(s + t * 8 + 4);
  float4 b0 = *(const float4*)(mk + t * 8);
  float4 b1 = *(const float4*)(mk + t * 8 + 4);
  float v[8] = {a0.x * scale + b0.x, a0.y * scale + b0.y,
                a0.z * scale + b0.z, a0.w * scale + b0.w,
                a1.x * scale + b1.x, a1.y * scale + b1.y,
                a1.z * scale + b1.z, a1.w * scale + b1.w};

  float mx = v[0];
#pragma unroll
  for (int j = 1; j < 8; ++j) mx = fmaxf(mx, v[j]);
  for (int o = 32; o > 0; o >>= 1) mx = fmaxf(mx, __shfl_xor(mx, o));

  __shared__ float redm[4];
  __shared__ float reds[4];
  const int w = t >> 6;
  if ((t & 63) == 0) redm[w] = mx;
  __syncthreads();
  mx = fmaxf(fmaxf(redm[0], redm[1]), fmaxf(redm[2], redm[3]));

  float e[8];
  float sum = 0.f;
#pragma unroll
  for (int j = 0; j < 8; ++j) { e[j] = __expf(v[j] - mx); sum += e[j]; }
  for (int o = 32; o > 0; o >>= 1) sum += __shfl_xor(sum, o);
  if ((t & 63) == 0) reds[w] = sum;
  __syncthreads();
  sum = reds[0] + reds[1] + reds[2] + reds[3];
  const float inv = 1.0f / sum;

  h8 o;
#pragma unroll
  for (int j = 0; j < 8; ++j) o[j] = (f16)(e[j] * inv);
  *(h8*)(P + row * (long)S_ + t * 8) = o;
}

extern "C" void kernel_launch(void* const* d_in, const int* in_sizes, int n_in,
                              void* d_out, int out_size, void* d_ws, size_t ws_size,
                              hipStream_t stream) {
  const float* x1 = (const float*)d_in[0];
  const float* x2 = (const float*)d_in[1];
  const float* x3 = (const float*)d_in[2];
  const float* mask = (const float*)d_in[3];
  const float* Wq = (const float*)d_in[4];
  const float* Wk = (const float*)d_in[5];
  const float* Wv = (const float*)d_in[6];

  const long nx = (long)B_ * S_ * D_;
  const long nw = (long)H_ * D_;
  const long nqkv = (long)B_ * S_ * H_;
  const long nsc = (long)B_ * S_ * S_;

  char* ws = (char*)d_ws;
  f16* x1h = (f16*)ws; ws += nx * 2;
  f16* x2h = (f16*)ws; ws += nx * 2;   // contiguous after x1h
  f16* x3h = (f16*)ws; ws += nx * 2;   // contiguous
  f16* wqh = (f16*)ws; ws += nw * 2;
  f16* wkh = (f16*)ws; ws += nw * 2;   // contiguous after wqh
  f16* wvh = (f16*)ws; ws += nw * 2;
  f16* qh  = (f16*)ws; ws += nqkv * 2;
  f16* kh  = (f16*)ws; ws += nqkv * 2; // contiguous after qh
  f16* vth = (f16*)ws; ws += nqkv * 2; // [b][h][s]
  float* sc = (float*)ws; ws += nsc * 4;
  f16* ph  = (f16*)ws; ws += nsc * 2;

  const int SMEM = 131072;
  hipFuncSetAttribute((const void*)gemm256p<3>, hipFuncAttributeMaxDynamicSharedMemorySize, SMEM);
  hipFuncSetAttribute((const void*)gemm256p<0>, hipFuncAttributeMaxDynamicSharedMemorySize, SMEM);

  cast_all<<<2048, 256, 0, stream>>>(x1, x2, x3, Wq, Wk, Wv,
                                     x1h, x2h, x3h, wqh, wkh, wvh);

  const dim3 blk(512);
  // QKV projections batched z=3: 32 x 4 x 3 = 384 blocks (1.5 rounds at 1 blk/CU)
  gemm256p<3><<<dim3(384), blk, SMEM, stream>>>(x1h, wqh, qh, 1024, 1024,
                                                nx, nw, nqkv, 32, 4);
  // scores[b] = Q[b] K[b]^T : 2048x2048x1024 x4, f32; 8 x 8 x 4 = 256 blocks (1 round)
  gemm256p<0><<<dim3(256), blk, SMEM, stream>>>(qh, kh, sc, 2048, 1024,
                                                (long)S_ * H_, (long)S_ * H_, (long)S_ * S_, 8, 8);
  // P = softmax(scores * 1/sqrt(H) + mask)
  softmax_rows<<<B_ * S_, 256, 0, stream>>>(sc, mask, ph, 0.03125f);
  // out[b] = P[b] (V^T[b])^T : 2048x1024x2048 x4, f32 to d_out; 8 x 4 x 4 = 128 blocks
  gemm256p<0><<<dim3(128), blk, SMEM, stream>>>(ph, vth, d_out, 1024, 2048,
                                                (long)S_ * S_, (long)S_ * H_, (long)S_ * H_, 8, 4);
}

// Round 8
// 221.147 us; speedup vs baseline: 1.2218x; 1.2218x over previous
//
#include <hip/hip_runtime.h>

typedef _Float16 f16;
typedef _Float16 h8 __attribute__((ext_vector_type(8)));
typedef float f4 __attribute__((ext_vector_type(4)));

typedef const __attribute__((address_space(1))) char gchar;
typedef __attribute__((address_space(3))) char lchar;

#define B_ 4
#define S_ 2048
#define D_ 1024
#define H_ 1024

template <int N>
__device__ __forceinline__ void vmwait() {
  if constexpr (N == 0) asm volatile("s_waitcnt vmcnt(0)" ::: "memory");
  else if constexpr (N == 4) asm volatile("s_waitcnt vmcnt(4)" ::: "memory");
}

// ---------------- fused fp32 -> fp16 cast of all six inputs ----------------
#define NGX (8388608L / 8)
#define NGW (1048576L / 8)

__global__ __launch_bounds__(256) void cast_all(
    const float* __restrict__ x1, const float* __restrict__ x2, const float* __restrict__ x3,
    const float* __restrict__ wq, const float* __restrict__ wk, const float* __restrict__ wv,
    f16* __restrict__ o1, f16* __restrict__ o2, f16* __restrict__ o3,
    f16* __restrict__ o4, f16* __restrict__ o5, f16* __restrict__ o6) {
  const long NG = 3 * NGX + 3 * NGW;
  long g = blockIdx.x * 256L + threadIdx.x;
  const long stride = (long)gridDim.x * 256L;
  for (; g < NG; g += stride) {
    const float* in;
    f16* out;
    long off;
    if (g < 3 * NGX) {
      const long w = g >> 20;
      off = (g - w * NGX) * 8;
      in = w == 0 ? x1 : (w == 1 ? x2 : x3);
      out = w == 0 ? o1 : (w == 1 ? o2 : o3);
    } else {
      const long gg = g - 3 * NGX;
      const long h = gg >> 17;
      off = (gg - h * NGW) * 8;
      in = h == 0 ? wq : (h == 1 ? wk : wv);
      out = h == 0 ? o4 : (h == 1 ? o5 : o6);
    }
    float4 u = *(const float4*)(in + off);
    float4 v = *(const float4*)(in + off + 4);
    h8 o;
    o[0] = (f16)u.x; o[1] = (f16)u.y; o[2] = (f16)u.z; o[3] = (f16)u.w;
    o[4] = (f16)v.x; o[5] = (f16)v.y; o[6] = (f16)v.z; o[7] = (f16)v.w;
    *(h8*)(out + off) = o;
  }
}

// ---------------- PROJ GEMM (r3-verbatim): C = A * B^T, 2-slot, syncthreads drain ----------
// Measured best for the projection shape (~750 TF). A [M,K], B [N,K] f16 row-major.
// OUT_MODE 1: f16  C[m*N+n]   (Q, K projections)
// OUT_MODE 2: f16 transposed per-batch: C[(m>>11)][n][m&2047]  (V^T projection)
#define TILE 128
#define BK 32

template <int OUT_MODE>
__global__ __launch_bounds__(256) void gemm_abt(const f16* __restrict__ A,
                                                const f16* __restrict__ Bm,
                                                void* __restrict__ C,
                                                int M, int N, int K,
                                                long sA, long sB, long sC) {
  const int bz = blockIdx.z;
  A += (long)bz * sA;
  Bm += (long)bz * sB;

  __shared__ __align__(16) f16 lA[2][TILE * BK];
  __shared__ __align__(16) f16 lB[2][TILE * BK];

  const int tid = threadIdx.x;
  const int lane = tid & 63;
  const int w = tid >> 6;
  const int wr = w >> 1, wc = w & 1;
  const int m0 = blockIdx.x * TILE;
  const int n0 = blockIdx.y * TILE;

  const int lr = lane >> 2;
  const int lc = (lane & 3) * 8;
  const f16* Abase = A + (long)(m0 + lr) * K + lc;
  const f16* Bbase = Bm + (long)(n0 + lr) * K + lc;

  const int fr = lane & 15;
  const int kg = (lane >> 4) * 8;

  f4 acc[4][4] = {};

  auto STAGE = [&](int buf, int k0) {
#pragma unroll
    for (int c = 0; c < 2; ++c) {
      const int br = w * 32 + c * 16;
      __builtin_amdgcn_global_load_lds(
          (gchar*)(Abase + (long)br * K + k0),
          (lchar*)&lA[buf][br * BK], 16, 0, 0);
      __builtin_amdgcn_global_load_lds(
          (gchar*)(Bbase + (long)br * K + k0),
          (lchar*)&lB[buf][br * BK], 16, 0, 0);
    }
  };

  STAGE(0, 0);
  __syncthreads();

  int cur = 0;
  for (int k0 = 0; k0 < K; k0 += BK) {
    if (k0 + BK < K) STAGE(cur ^ 1, k0 + BK);

    h8 af[4], bf[4];
#pragma unroll
    for (int i = 0; i < 4; ++i) {
      af[i] = *(const h8*)&lA[cur][(wr * 64 + i * 16 + fr) * BK + kg];
      bf[i] = *(const h8*)&lB[cur][(wc * 64 + i * 16 + fr) * BK + kg];
    }
#pragma unroll
    for (int mi = 0; mi < 4; ++mi)
#pragma unroll
      for (int ni = 0; ni < 4; ++ni)
        acc[mi][ni] = __builtin_amdgcn_mfma_f32_16x16x32_f16(af[mi], bf[ni], acc[mi][ni], 0, 0, 0);

    __syncthreads();
    cur ^= 1;
  }

  const int fq = (lane >> 4) * 4;
#pragma unroll
  for (int mi = 0; mi < 4; ++mi) {
#pragma unroll
    for (int ni = 0; ni < 4; ++ni) {
#pragma unroll
      for (int i = 0; i < 4; ++i) {
        const int row = m0 + wr * 64 + mi * 16 + fq + i;
        const int col = n0 + wc * 64 + ni * 16 + fr;
        const float val = acc[mi][ni][i];
        if constexpr (OUT_MODE == 1) {
          f16* Cp = (f16*)C + (long)bz * sC;
          Cp[(long)row * N + col] = (f16)val;
        } else {
          f16* Cp = (f16*)C;
          const int b = row >> 11, sr = row & 2047;
          Cp[((long)b * N + col) * 2048 + sr] = (f16)val;
        }
      }
    }
  }
}

// ---------- Big-K GEMM (r6-verbatim): 128x128/BK32, 3-slot ring, counted vmcnt(4), T2 swizzle ----
// MODE 0: f32 C[m*N+n] (+bz*sC).  MODE 4: f16 C[m*N+n] (+bz*sC)  (scores).
template <int MODE>
__global__ __launch_bounds__(256, 3) void gemm128(const f16* __restrict__ A,
                                                  const f16* __restrict__ Bm,
                                                  void* __restrict__ C,
                                                  int N, int K,
                                                  long sA, long sB, long sC,
                                                  int gx, int gy) {
  __shared__ __align__(16) f16 smem[3 * 8192];  // 48 KiB

  const int cpx = gridDim.x >> 3;
  const int wgid = (blockIdx.x & 7) * cpx + (blockIdx.x >> 3);
  const int by = wgid % gy;
  const int bx = (wgid / gy) % gx;
  const int bz = wgid / (gy * gx);
  A += (long)bz * sA;
  Bm += (long)bz * sB;
  const int m0 = bx * 128, n0 = by * 128;

  const int tid = threadIdx.x;
  const int lane = tid & 63;
  const int w = tid >> 6;
  const int wr = w >> 1, wc = w & 1;
  const int fr = lane & 15;
  const int g = lane >> 4;

  const int r0 = tid >> 2;
  const int s = tid & 3;

  auto STAGE = [&](int sl, int t) {
    const long k0 = (long)t * 32;
#pragma unroll
    for (int c = 0; c < 2; ++c) {
      const int row = c * 64 + r0;
      const int scol = (s ^ ((row >> 1) & 3)) * 8;
      __builtin_amdgcn_global_load_lds(
          (gchar*)(A + (long)(m0 + row) * K + k0 + scol),
          (lchar*)(smem + sl * 8192 + (c * 256 + w * 64) * 8), 16, 0, 0);
      __builtin_amdgcn_global_load_lds(
          (gchar*)(Bm + (long)(n0 + row) * K + k0 + scol),
          (lchar*)(smem + sl * 8192 + 4096 + (c * 256 + w * 64) * 8), 16, 0, 0);
    }
  };

  auto RD = [&](int sl, int mat, int r) -> h8 {
    return *(const h8*)(smem + sl * 8192 + mat * 4096 + (r * 4 + (g ^ ((r >> 1) & 3))) * 8);
  };

  f4 acc[4][4] = {};
  const int NT = K >> 5;

  STAGE(0, 0);
  STAGE(1, 1);
  vmwait<4>();
  __builtin_amdgcn_s_barrier();

  int sl = 0;
  for (int t = 0; t < NT; ++t) {
    h8 af[4], bf[4];
#pragma unroll
    for (int i = 0; i < 4; ++i) {
      af[i] = RD(sl, 0, wr * 64 + i * 16 + fr);
      bf[i] = RD(sl, 1, wc * 64 + i * 16 + fr);
    }
    const int ts = (t + 2 < NT) ? t + 2 : NT - 1;
    int ss = sl + 2; if (ss >= 3) ss -= 3;
    STAGE(ss, ts);
    vmwait<4>();
    asm volatile("s_waitcnt lgkmcnt(0)" ::: "memory");
    __builtin_amdgcn_sched_barrier(0);
    __builtin_amdgcn_s_setprio(1);
#pragma unroll
    for (int mi = 0; mi < 4; ++mi)
#pragma unroll
      for (int ni = 0; ni < 4; ++ni)
        acc[mi][ni] = __builtin_amdgcn_mfma_f32_16x16x32_f16(af[mi], bf[ni], acc[mi][ni], 0, 0, 0);
    __builtin_amdgcn_s_setprio(0);
    __builtin_amdgcn_s_barrier();
    sl = (sl + 1 == 3) ? 0 : sl + 1;
  }
  vmwait<0>();

  const int fq = g * 4;
#pragma unroll
  for (int mi = 0; mi < 4; ++mi) {
#pragma unroll
    for (int ni = 0; ni < 4; ++ni) {
#pragma unroll
      for (int i = 0; i < 4; ++i) {
        const int row = m0 + wr * 64 + mi * 16 + fq + i;
        const int col = n0 + wc * 64 + ni * 16 + fr;
        const float val = acc[mi][ni][i];
        if constexpr (MODE == 0) {
          float* Cp = (float*)C + (long)bz * sC;
          Cp[(long)row * N + col] = val;
        } else {
          f16* Cp = (f16*)C + (long)bz * sC;
          Cp[(long)row * N + col] = (f16)val;
        }
      }
    }
  }
}

// ---------------- fused scale + mask + softmax, scores f16 -> P f16 ----------------
__global__ __launch_bounds__(256) void softmax_rows(const f16* __restrict__ Sc,
                                                    const float* __restrict__ mask,
                                                    f16* __restrict__ P, float scale) {
  const long row = blockIdx.x;
  const f16* s = Sc + row * (long)S_;
  const float* mk = mask + row * (long)S_;
  const int t = threadIdx.x;

  h8 sv = *(const h8*)(s + t * 8);
  float4 b0 = *(const float4*)(mk + t * 8);
  float4 b1 = *(const float4*)(mk + t * 8 + 4);
  float v[8] = {(float)sv[0] * scale + b0.x, (float)sv[1] * scale + b0.y,
                (float)sv[2] * scale + b0.z, (float)sv[3] * scale + b0.w,
                (float)sv[4] * scale + b1.x, (float)sv[5] * scale + b1.y,
                (float)sv[6] * scale + b1.z, (float)sv[7] * scale + b1.w};

  float mx = v[0];
#pragma unroll
  for (int j = 1; j < 8; ++j) mx = fmaxf(mx, v[j]);
  for (int o = 32; o > 0; o >>= 1) mx = fmaxf(mx, __shfl_xor(mx, o));

  __shared__ float redm[4];
  __shared__ float reds[4];
  const int w = t >> 6;
  if ((t & 63) == 0) redm[w] = mx;
  __syncthreads();
  mx = fmaxf(fmaxf(redm[0], redm[1]), fmaxf(redm[2], redm[3]));

  float e[8];
  float sum = 0.f;
#pragma unroll
  for (int j = 0; j < 8; ++j) { e[j] = __expf(v[j] - mx); sum += e[j]; }
  for (int o = 32; o > 0; o >>= 1) sum += __shfl_xor(sum, o);
  if ((t & 63) == 0) reds[w] = sum;
  __syncthreads();
  sum = reds[0] + reds[1] + reds[2] + reds[3];
  const float inv = 1.0f / sum;

  h8 o;
#pragma unroll
  for (int j = 0; j < 8; ++j) o[j] = (f16)(e[j] * inv);
  *(h8*)(P + row * (long)S_ + t * 8) = o;
}

extern "C" void kernel_launch(void* const* d_in, const int* in_sizes, int n_in,
                              void* d_out, int out_size, void* d_ws, size_t ws_size,
                              hipStream_t stream) {
  const float* x1 = (const float*)d_in[0];
  const float* x2 = (const float*)d_in[1];
  const float* x3 = (const float*)d_in[2];
  const float* mask = (const float*)d_in[3];
  const float* Wq = (const float*)d_in[4];
  const float* Wk = (const float*)d_in[5];
  const float* Wv = (const float*)d_in[6];

  const long nx = (long)B_ * S_ * D_;
  const long nw = (long)H_ * D_;
  const long nqkv = (long)B_ * S_ * H_;
  const long nsc = (long)B_ * S_ * S_;

  char* ws = (char*)d_ws;
  f16* x1h = (f16*)ws; ws += nx * 2;
  f16* x2h = (f16*)ws; ws += nx * 2;
  f16* x3h = (f16*)ws; ws += nx * 2;
  f16* wqh = (f16*)ws; ws += nw * 2;
  f16* wkh = (f16*)ws; ws += nw * 2;
  f16* wvh = (f16*)ws; ws += nw * 2;
  f16* qh  = (f16*)ws; ws += nqkv * 2;
  f16* kh  = (f16*)ws; ws += nqkv * 2;
  f16* vth = (f16*)ws; ws += nqkv * 2;   // [b][h][s]
  f16* sc  = (f16*)ws; ws += nsc * 2;    // scores f16
  f16* ph  = (f16*)ws; ws += nsc * 2;

  cast_all<<<2048, 256, 0, stream>>>(x1, x2, x3, Wq, Wk, Wv,
                                     x1h, x2h, x3h, wqh, wkh, wvh);

  const dim3 blk(256);
  // Projections: r3 structure, 3 separate dispatches, 512 blocks each
  gemm_abt<1><<<dim3(64, 8, 1), blk, 0, stream>>>(x1h, wqh, qh, 8192, 1024, 1024, 0, 0, 0);
  gemm_abt<1><<<dim3(64, 8, 1), blk, 0, stream>>>(x2h, wkh, kh, 8192, 1024, 1024, 0, 0, 0);
  gemm_abt<2><<<dim3(64, 8, 1), blk, 0, stream>>>(x3h, wvh, vth, 8192, 1024, 1024, 0, 0, 0);
  // scores[b] = Q[b] K[b]^T -> f16 : 16 x 16 x 4 = 1024 blocks
  gemm128<4><<<dim3(1024), blk, 0, stream>>>(qh, kh, sc, 2048, 1024,
                                             (long)S_ * H_, (long)S_ * H_, (long)S_ * S_, 16, 16);
  // P = softmax(scores * 1/sqrt(H) + mask)
  softmax_rows<<<B_ * S_, 256, 0, stream>>>(sc, mask, ph, 0.03125f);
  // out[b] = P[b] (V^T[b])^T : 16 x 8 x 4 = 512 blocks
  gemm128<0><<<dim3(512), blk, 0, stream>>>(ph, vth, d_out, 1024, 2048,
                                            (long)S_ * S_, (long)S_ * H_, (long)S_ * H_, 16, 8);
}